// Round 13
// baseline (475.833 us; speedup 1.0000x reference)
//
#include <hip/hip_runtime.h>
#include <hip/hip_bf16.h>

// SAICNet: encoder = round-4/11 proven structure with AGPR-pinned weights.
// vs round-12 (failed 9.77e-4): accumulation order restored to the EXACT
// round-11 sequence (E, H0h, L0*H0h, H0*H0l, H1*H1h, L1*H1h, H1*H1l) —
// term 1 and term 7 are builtins (compiler owns init & read hazards),
// terms 2-6 are inline-asm MFMA with B pinned in AGPRs (48 regs freed).
// Decoder = proven 512-thread / 8-scene version.

typedef short short8 __attribute__((ext_vector_type(8)));
typedef float f32x4  __attribute__((ext_vector_type(4)));

__device__ __forceinline__ float rcp_(float x) { return __builtin_amdgcn_rcpf(x); }
__device__ __forceinline__ float sigmoid_(float x) { return rcp_(1.0f + __expf(-x)); }
__device__ __forceinline__ float tanh_(float x) {
    float e = __expf(-2.0f * fabsf(x));             // in (0,1], overflow-free
    float t = (1.0f - e) * rcp_(1.0f + e);
    return copysignf(t, x);
}
__device__ __forceinline__ short bf16rne_(float v) {
    unsigned u = __builtin_bit_cast(unsigned, v);
    u += 0x7FFF + ((u >> 16) & 1);
    return (short)(u >> 16);
}
__device__ __forceinline__ short bf16tr_(float v) {
    return (short)(__builtin_bit_cast(unsigned, v) >> 16);
}
__device__ __forceinline__ float b2f_(short s) {
    return __builtin_bit_cast(float, ((unsigned)(unsigned short)s) << 16);
}
__device__ __forceinline__ void split_(float w, short& h, short& l) {
    h = bf16tr_(w);
    l = bf16rne_(w - b2f_(h));
}

// MFMA with B operand pinned to AGPR ("a" constraint). D tied to C ("+v").
// Used only mid-chain (terms 2-6): inputs come from compiler loads (dep-
// tracked), output only feeds further MFMAs' C (D->C chaining, 0 wait states).
#define MFMA_AG(accv, av, bv) \
    __asm__("v_mfma_f32_16x16x32_bf16 %0, %1, %2, %0" : "+v"(accv) : "v"(av), "a"(bv))

#define XSTR 168   // shorts/row: [emb 0..31 | h_hi 32..95 | h_lo 96..159 | pad 8]

// ---------------------------------------------------------------------------
// Encoder + pooling. 256 threads = 4 waves; block = 64 agents (2 scenes).
// Wave p owns gate cols {64g + 16p + l15 : g=0..3} for ALL 64 agents.
// Weights: Bih + BhhL1 in VGPRs (16 regs, builtin MFMA terms 1 & 7);
// BhhH0, BhhL0, BhhH1 in AGPRs (48 regs, asm MFMA terms 2-6).
// X double-buffered in LDS -> ONE barrier per step. c fp32 in registers.
// MFMA 16x16x32 bf16: A row=l&15, k=(l>>4)*8+i; D col=l&15, row=(l>>4)*4+reg.
// ---------------------------------------------------------------------------
__global__ __launch_bounds__(256, 3) void enc_pool_kernel(
    const float* __restrict__ hist,      // [T,N,2]
    const float* __restrict__ hist_pos,  // [N,2]
    const float* __restrict__ W_ie,      // [2,32]
    const float* __restrict__ b_ie,      // [32]
    const float* __restrict__ Wih,       // [32,256]
    const float* __restrict__ Whh,       // [64,256]
    const float* __restrict__ bih,       // [256]
    const float* __restrict__ bhh,       // [256]
    const float* __restrict__ Wse,       // [2,64]
    const float* __restrict__ bse,       // [64]
    const float* __restrict__ Wmp,       // [128,64]
    const float* __restrict__ bmp,       // [64]
    float* __restrict__ encO,            // [S,128] (ws)
    int N, int T)
{
    __shared__ __align__(16) short sX[2][64 * XSTR];  // 43008 B
    __shared__ float sIE[96];    // W_ie(64)+b_ie(32)
    __shared__ float sWse[192];  // Wse(128)+bse(64)
    __shared__ float sTgt[128];  // exact fp32 h of scene-first agents

    const int tid = threadIdx.x;
    const int l15 = tid & 15;
    const int l4  = (tid & 63) >> 4;
    const int p   = tid >> 6;           // wave id = col-tile owner
    const int n0  = blockIdx.x << 6;    // first agent of block
    const int jcol = (p << 4) + l15;    // h column this lane owns

    // ---- W fragments ----
    short8 Bih[4];     // VGPR: emb k-tile, RNE bf16 (term 1, builtin)
    short8 BL1v[4];    // VGPR: h k-tile 1 lo      (term 7, builtin)
    short8 AH0[4];     // AGPR: h k-tile 0 hi      (terms 2,3, asm)
    short8 AL0[4];     // AGPR: h k-tile 0 lo      (term 4, asm)
    short8 AH1[4];     // AGPR: h k-tile 1 hi      (terms 5,6, asm)
    float bias[4];
#pragma unroll
    for (int n = 0; n < 4; ++n) {
        int c = (n << 6) + jcol;
        short8 bi;
#pragma unroll
        for (int i = 0; i < 8; ++i)
            bi[i] = bf16rne_(Wih[(l4 * 8 + i) * 256 + c]);
        Bih[n] = bi;
        short8 h0, l0, h1, l1;
#pragma unroll
        for (int i = 0; i < 8; ++i) {
            short hh, ll;
            split_(Whh[(l4 * 8 + i) * 256 + c], hh, ll);
            h0[i] = hh; l0[i] = ll;
            split_(Whh[(32 + l4 * 8 + i) * 256 + c], hh, ll);
            h1[i] = hh; l1[i] = ll;
        }
        AH0[n] = h0; AL0[n] = l0;
        AH1[n] = h1; BL1v[n] = l1;
        bias[n] = bih[c] + bhh[c];
    }

    // ---- zero buf0, stage small tables ----
    for (int i = tid; i < 64 * XSTR / 2; i += 256) ((int*)sX[0])[i] = 0;
    if (tid < 64)       sIE[tid] = W_ie[tid];
    else if (tid < 96)  sIE[tid] = b_ie[tid - 64];
    if (tid < 128)      sWse[tid] = Wse[tid];
    else if (tid < 192) sWse[tid] = bse[tid - 128];
    __syncthreads();

    const float2* hist2 = (const float2*)hist;
    const int ag = tid >> 2;          // agent this thread embeds (0..63)
    const int eb = (tid & 3) << 3;    // its 8 emb dims

    auto emb_write = [&](int t) {
        float2 xy = hist2[(size_t)t * N + n0 + ag];
        short8 ev;
#pragma unroll
        for (int q = 0; q < 8; ++q) {
            int e = eb + q;
            float v = fmaf(xy.x, sIE[e], fmaf(xy.y, sIE[32 + e], sIE[64 + e]));
            ev[q] = bf16rne_(fmaxf(v, 0.0f));
        }
        *(short8*)(sX[t & 1] + ag * XSTR + eb) = ev;
    };
    emb_write(0);
    __syncthreads();

    float cst[4][4];
#pragma unroll
    for (int m = 0; m < 4; ++m)
#pragma unroll
        for (int r = 0; r < 4; ++r) cst[m][r] = 0.0f;

    for (int t = 0; t < T; ++t) {
        const short* bR = sX[t & 1];
        short* bW = sX[(t + 1) & 1];
#pragma unroll
        for (int m = 0; m < 4; ++m) {
            const short* row = bR + ((m << 4) + l15) * XSTR + l4 * 8;
            short8 aE  = *(const short8*)(row);
            short8 aH0 = *(const short8*)(row + 32);
            short8 aH1 = *(const short8*)(row + 64);
            short8 aL0 = *(const short8*)(row + 96);
            short8 aL1 = *(const short8*)(row + 128);
            f32x4 acc[4];
#pragma unroll
            for (int n = 0; n < 4; ++n)
                acc[n] = (f32x4){bias[n], bias[n], bias[n], bias[n]};
            // EXACT round-11 accumulation order:
#pragma unroll
            for (int n = 0; n < 4; ++n)   // 1: E * Wih            (builtin)
                acc[n] = __builtin_amdgcn_mfma_f32_16x16x32_bf16(aE, Bih[n], acc[n], 0, 0, 0);
#pragma unroll
            for (int n = 0; n < 4; ++n) MFMA_AG(acc[n], aH0, AH0[n]);  // 2: hHi0*WH0
#pragma unroll
            for (int n = 0; n < 4; ++n) MFMA_AG(acc[n], aL0, AH0[n]);  // 3: hLo0*WH0
#pragma unroll
            for (int n = 0; n < 4; ++n) MFMA_AG(acc[n], aH0, AL0[n]);  // 4: hHi0*WL0
#pragma unroll
            for (int n = 0; n < 4; ++n) MFMA_AG(acc[n], aH1, AH1[n]);  // 5: hHi1*WH1
#pragma unroll
            for (int n = 0; n < 4; ++n) MFMA_AG(acc[n], aL1, AH1[n]);  // 6: hLo1*WH1
#pragma unroll
            for (int n = 0; n < 4; ++n)   // 7: hHi1 * WL1         (builtin)
                acc[n] = __builtin_amdgcn_mfma_f32_16x16x32_bf16(aH1, BL1v[n], acc[n], 0, 0, 0);
#pragma unroll
            for (int r = 0; r < 4; ++r) {
                float i_ = sigmoid_(acc[0][r]);
                float f_ = sigmoid_(acc[1][r]);
                float g_ = tanh_(acc[2][r]);
                float o_ = sigmoid_(acc[3][r]);
                cst[m][r] = fmaf(f_, cst[m][r], i_ * g_);
                float h = o_ * tanh_(cst[m][r]);
                short hh = bf16tr_(h);
                short hl = bf16rne_(h - b2f_(hh));
                int rw = (m << 4) + (l4 << 2) + r;
                bW[rw * XSTR + 32 + jcol] = hh;
                bW[rw * XSTR + 96 + jcol] = hl;
                if (t == T - 1 && l4 == 0 && r == 0 && (m & 1) == 0)
                    sTgt[(m >> 1) * 64 + jcol] = h;   // exact scene-first h
            }
        }
        if (t + 1 < T) emb_write(t + 1);
        __syncthreads();
    }

    // ---- social pooling: rel into dead buffer, Wmp in regs, MFMA ----
    short* rb = sX[(T + 1) & 1];      // buffer NOT holding final h
    const short* hb = sX[T & 1];      // final h (hi+lo)
    {
        const float2* pos2 = (const float2*)hist_pos;
        float2 pa = pos2[n0 + ag];
        float2 pb = pos2[n0 + (ag & 32)];   // scene-first agent (P=32)
        float px = pa.x - pb.x, py = pa.y - pb.y;
        int ebq = (tid & 3) << 4;
        short8 r0v, r1v;
#pragma unroll
        for (int q = 0; q < 8; ++q) {
            int e = ebq + q;
            float v = fmaf(px, sWse[e], fmaf(py, sWse[64 + e], sWse[128 + e]));
            r0v[q] = bf16rne_(fmaxf(v, 0.0f));
        }
#pragma unroll
        for (int q = 0; q < 8; ++q) {
            int e = ebq + 8 + q;
            float v = fmaf(px, sWse[e], fmaf(py, sWse[64 + e], sWse[128 + e]));
            r1v[q] = bf16rne_(fmaxf(v, 0.0f));
        }
        *(short8*)(rb + ag * XSTR + ebq)     = r0v;
        *(short8*)(rb + ag * XSTR + ebq + 8) = r1v;
    }
    // Wmp fragments: rows kt*32.. (k<64: h, k>=64: rel), col = jcol
    short8 BmH[4], BmL[4];
#pragma unroll
    for (int kt = 0; kt < 4; ++kt) {
        short8 bh, bl;
#pragma unroll
        for (int i = 0; i < 8; ++i) {
            short hh, ll; split_(Wmp[(kt * 32 + l4 * 8 + i) * 64 + jcol], hh, ll);
            bh[i] = hh; bl[i] = ll;
        }
        BmH[kt] = bh; BmL[kt] = bl;
    }
    float bmpv = bmp[jcol];
    __syncthreads();

    float smax0 = -3.4e38f, smax1 = -3.4e38f;
#pragma unroll
    for (int m = 0; m < 4; ++m) {
        const short* row  = hb + ((m << 4) + l15) * XSTR + l4 * 8;
        const short* rrow = rb + ((m << 4) + l15) * XSTR + l4 * 8;
        short8 h0 = *(const short8*)(row + 32);
        short8 h1 = *(const short8*)(row + 64);
        short8 q0 = *(const short8*)(row + 96);
        short8 q1 = *(const short8*)(row + 128);
        short8 r0 = *(const short8*)(rrow);
        short8 r1 = *(const short8*)(rrow + 32);
        f32x4 pc = (f32x4){bmpv, bmpv, bmpv, bmpv};
        pc = __builtin_amdgcn_mfma_f32_16x16x32_bf16(h0, BmH[0], pc, 0, 0, 0);
        pc = __builtin_amdgcn_mfma_f32_16x16x32_bf16(q0, BmH[0], pc, 0, 0, 0);
        pc = __builtin_amdgcn_mfma_f32_16x16x32_bf16(h0, BmL[0], pc, 0, 0, 0);
        pc = __builtin_amdgcn_mfma_f32_16x16x32_bf16(h1, BmH[1], pc, 0, 0, 0);
        pc = __builtin_amdgcn_mfma_f32_16x16x32_bf16(q1, BmH[1], pc, 0, 0, 0);
        pc = __builtin_amdgcn_mfma_f32_16x16x32_bf16(h1, BmL[1], pc, 0, 0, 0);
        pc = __builtin_amdgcn_mfma_f32_16x16x32_bf16(r0, BmH[2], pc, 0, 0, 0);
        pc = __builtin_amdgcn_mfma_f32_16x16x32_bf16(r0, BmL[2], pc, 0, 0, 0);
        pc = __builtin_amdgcn_mfma_f32_16x16x32_bf16(r1, BmH[3], pc, 0, 0, 0);
        pc = __builtin_amdgcn_mfma_f32_16x16x32_bf16(r1, BmL[3], pc, 0, 0, 0);
        float mx = fmaxf(fmaxf(pc[0], pc[1]), fmaxf(pc[2], pc[3]));
        mx = fmaxf(mx, 0.0f);   // relu(max) == max(relu)
        if (m < 2) smax0 = fmaxf(smax0, mx); else smax1 = fmaxf(smax1, mx);
    }
    smax0 = fmaxf(smax0, __shfl_xor(smax0, 16));
    smax0 = fmaxf(smax0, __shfl_xor(smax0, 32));
    smax1 = fmaxf(smax1, __shfl_xor(smax1, 16));
    smax1 = fmaxf(smax1, __shfl_xor(smax1, 32));
    if (l4 == 0) {
        int sg = blockIdx.x << 1;
        encO[sg * 128 + jcol]      = smax0;
        encO[sg * 128 + 64 + jcol] = sTgt[jcol];
    } else if (l4 == 1) {
        int sg = (blockIdx.x << 1) + 1;
        encO[sg * 128 + jcol]      = smax1;
        encO[sg * 128 + 64 + jcol] = sTgt[64 + jcol];
    }
}

// ---------------------------------------------------------------------------
// Decoder: WG = 512 threads = 8 waves = 8 scenes (proven round 11).
// ---------------------------------------------------------------------------
__global__ __launch_bounds__(512, 2) void dec_kernel(
    const float* __restrict__ enc,    // [S,128] (ws)
    const float* __restrict__ Wih_d,  // [128,256]
    const float* __restrict__ Whh_d,  // [64,256]
    const float* __restrict__ bih_d,  // [256]
    const float* __restrict__ bhh_d,  // [256]
    const float* __restrict__ Wop,    // [64,2]
    const float* __restrict__ bop,    // [2]
    float* __restrict__ out,          // [TOUT,S,2]
    int S, int TOUT)
{
    __shared__ __align__(16) float sWh[16384];   // [k64][j64][G4]
    __shared__ __align__(16) float sHd[512];     // [w8][j64]

    const int tid = threadIdx.x;
    const int j = tid & 63;
    const int w = tid >> 6;
    const int s = (blockIdx.x << 3) + w;

    for (int idx = tid; idx < 64 * 256; idx += 512) {
        int k = idx >> 8, col = idx & 255;
        sWh[((k << 6) | (col & 63)) * 4 + (col >> 6)] = Whh_d[idx];
    }
    sHd[tid] = 0.0f;

    float gx0 = bih_d[j]       + bhh_d[j];
    float gx1 = bih_d[64 + j]  + bhh_d[64 + j];
    float gx2 = bih_d[128 + j] + bhh_d[128 + j];
    float gx3 = bih_d[192 + j] + bhh_d[192 + j];
    for (int k = 0; k < 128; ++k) {
        float ev = enc[s * 128 + k];
        const float* col = Wih_d + k * 256;
        gx0 = fmaf(ev, col[j], gx0);
        gx1 = fmaf(ev, col[64 + j], gx1);
        gx2 = fmaf(ev, col[128 + j], gx2);
        gx3 = fmaf(ev, col[192 + j], gx3);
    }
    float wop0 = Wop[j * 2], wop1 = Wop[j * 2 + 1];
    float bop0 = bop[0], bop1 = bop[1];

    __syncthreads();

    const float4* Wh4 = reinterpret_cast<const float4*>(sWh);
    const float4* H4  = reinterpret_cast<const float4*>(sHd);

    float c = 0.0f;
    for (int t = 0; t < TOUT; ++t) {
        float g0 = gx0, g1 = gx1, g2 = gx2, g3 = gx3;
#pragma unroll 4
        for (int kq = 0; kq < 16; ++kq) {
            float4 hv = H4[(w << 4) + kq];
            float4 w0 = Wh4[((kq * 4 + 0) << 6) + j];
            float4 w1 = Wh4[((kq * 4 + 1) << 6) + j];
            float4 w2 = Wh4[((kq * 4 + 2) << 6) + j];
            float4 w3 = Wh4[((kq * 4 + 3) << 6) + j];
            g0 += hv.x * w0.x + hv.y * w1.x + hv.z * w2.x + hv.w * w3.x;
            g1 += hv.x * w0.y + hv.y * w1.y + hv.z * w2.y + hv.w * w3.y;
            g2 += hv.x * w0.z + hv.y * w1.z + hv.z * w2.z + hv.w * w3.z;
            g3 += hv.x * w0.w + hv.y * w1.w + hv.z * w2.w + hv.w * w3.w;
        }
        float i_ = sigmoid_(g0);
        float f_ = sigmoid_(g1);
        float gg = tanh_(g2);
        float o_ = sigmoid_(g3);
        c = fmaf(f_, c, i_ * gg);
        float h = o_ * tanh_(c);

        float r0 = h * wop0, r1 = h * wop1;
#pragma unroll
        for (int off = 32; off > 0; off >>= 1) {
            r0 += __shfl_xor(r0, off);
            r1 += __shfl_xor(r1, off);
        }
        if (j == 0) {
            float* op = out + ((size_t)t * S + s) * 2;
            op[0] = r0 + bop0;
            op[1] = r1 + bop1;
        }
        sHd[(w << 6) + j] = h;   // own row; intra-wave ordering suffices
    }
}

extern "C" void kernel_launch(void* const* d_in, const int* in_sizes, int n_in,
                              void* d_out, int out_size, void* d_ws, size_t ws_size,
                              hipStream_t stream) {
    (void)n_in; (void)ws_size;
    const float* hist     = (const float*)d_in[0];
    const float* hist_pos = (const float*)d_in[1];
    const float* W_ie     = (const float*)d_in[2];
    const float* b_ie     = (const float*)d_in[3];
    const float* Wih_e    = (const float*)d_in[4];
    const float* Whh_e    = (const float*)d_in[5];
    const float* bih_e    = (const float*)d_in[6];
    const float* bhh_e    = (const float*)d_in[7];
    const float* Wse      = (const float*)d_in[8];
    const float* bse      = (const float*)d_in[9];
    const float* Wmp      = (const float*)d_in[10];
    const float* bmp      = (const float*)d_in[11];
    const float* Wih_d    = (const float*)d_in[12];
    const float* Whh_d    = (const float*)d_in[13];
    const float* bih_d    = (const float*)d_in[14];
    const float* bhh_d    = (const float*)d_in[15];
    const float* Wop      = (const float*)d_in[16];
    const float* bop      = (const float*)d_in[17];

    const int N = in_sizes[1] / 2;
    const int T = in_sizes[0] / (N * 2);
    const int S = in_sizes[18] - 1;
    const int TOUT = out_size / (S * 2);

    float* enc = (float*)d_ws;   // [S,128] = 2 MB

    enc_pool_kernel<<<dim3(N / 64), dim3(256), 0, stream>>>(
        hist, hist_pos, W_ie, b_ie, Wih_e, Whh_e, bih_e, bhh_e,
        Wse, bse, Wmp, bmp, enc, N, T);

    dec_kernel<<<dim3(S / 8), dim3(512), 0, stream>>>(
        enc, Wih_d, Whh_d, bih_d, bhh_d, Wop, bop, (float*)d_out, S, TOUT);
}

// Round 14
// 428.277 us; speedup vs baseline: 1.1110x; 1.1110x over previous
//
#include <hip/hip_runtime.h>
#include <hip/hip_bf16.h>

// SAICNet: encoder = round-4/11 measured-best kernel with ONE delta:
// the next-step hist load is issued at the TOP of the t-loop (before the
// 28-MFMA phase) so its HBM/L2 latency hides under compute; the embedding
// is computed+stored from the prefetched value after the m-loop. Identical
// FP ops in identical order -> numerics bit-for-bit = round 11 (2.441e-4).
// Decoder = proven 512-thread / 8-scene version.

typedef short short8 __attribute__((ext_vector_type(8)));
typedef float f32x4  __attribute__((ext_vector_type(4)));

__device__ __forceinline__ float rcp_(float x) { return __builtin_amdgcn_rcpf(x); }
__device__ __forceinline__ float sigmoid_(float x) { return rcp_(1.0f + __expf(-x)); }
__device__ __forceinline__ float tanh_(float x) {
    float e = __expf(-2.0f * fabsf(x));             // in (0,1], overflow-free
    float t = (1.0f - e) * rcp_(1.0f + e);
    return copysignf(t, x);
}
__device__ __forceinline__ short bf16rne_(float v) {
    unsigned u = __builtin_bit_cast(unsigned, v);
    u += 0x7FFF + ((u >> 16) & 1);
    return (short)(u >> 16);
}
__device__ __forceinline__ short bf16tr_(float v) {
    return (short)(__builtin_bit_cast(unsigned, v) >> 16);
}
__device__ __forceinline__ float b2f_(short s) {
    return __builtin_bit_cast(float, ((unsigned)(unsigned short)s) << 16);
}
__device__ __forceinline__ void split_(float w, short& h, short& l) {
    h = bf16tr_(w);
    l = bf16rne_(w - b2f_(h));
}

#define XSTR 168   // shorts/row: [emb 0..31 | h_hi 32..95 | h_lo 96..159 | pad 8]

// ---------------------------------------------------------------------------
// Encoder + pooling. 256 threads = 4 waves; block = 64 agents (2 scenes).
// Wave p owns gate cols {64g + 16p + l15 : g=0..3} for ALL 64 agents.
// Weights in VGPRs (80 regs): Bih RNE-bf16, Bhh split hi/lo (drop hlo*Wlo).
// X double-buffered in LDS -> ONE barrier per step. c fp32 in registers.
// A-frags loaded upfront (5 b128) -> max ILP across the 28-MFMA phase.
// MFMA 16x16x32 bf16: A row=l&15, k=(l>>4)*8+i; D col=l&15, row=(l>>4)*4+reg.
// ---------------------------------------------------------------------------
__global__ __launch_bounds__(256, 3) void enc_pool_kernel(
    const float* __restrict__ hist,      // [T,N,2]
    const float* __restrict__ hist_pos,  // [N,2]
    const float* __restrict__ W_ie,      // [2,32]
    const float* __restrict__ b_ie,      // [32]
    const float* __restrict__ Wih,       // [32,256]
    const float* __restrict__ Whh,       // [64,256]
    const float* __restrict__ bih,       // [256]
    const float* __restrict__ bhh,       // [256]
    const float* __restrict__ Wse,       // [2,64]
    const float* __restrict__ bse,       // [64]
    const float* __restrict__ Wmp,       // [128,64]
    const float* __restrict__ bmp,       // [64]
    float* __restrict__ encO,            // [S,128] (ws)
    int N, int T)
{
    __shared__ __align__(16) short sX[2][64 * XSTR];  // 43008 B
    __shared__ float sIE[96];    // W_ie(64)+b_ie(32)
    __shared__ float sWse[192];  // Wse(128)+bse(64)
    __shared__ float sTgt[128];  // exact fp32 h of scene-first agents

    const int tid = threadIdx.x;
    const int l15 = tid & 15;
    const int l4  = (tid & 63) >> 4;
    const int p   = tid >> 6;           // wave id = col-tile owner
    const int n0  = blockIdx.x << 6;    // first agent of block
    const int jcol = (p << 4) + l15;    // h column this lane owns

    // ---- W fragments into registers ----
    short8 Bih[4];                  // emb k-tile, RNE bf16, per gate n
    short8 BhhH[2][4], BhhL[2][4];  // h k-tiles, split hi/lo, per gate n
    float bias[4];
#pragma unroll
    for (int n = 0; n < 4; ++n) {
        int c = (n << 6) + jcol;
        short8 bi;
#pragma unroll
        for (int i = 0; i < 8; ++i)
            bi[i] = bf16rne_(Wih[(l4 * 8 + i) * 256 + c]);
        Bih[n] = bi;
#pragma unroll
        for (int kt = 0; kt < 2; ++kt) {
            short8 ch, cl;
#pragma unroll
            for (int i = 0; i < 8; ++i) {
                short hh, ll; split_(Whh[(kt * 32 + l4 * 8 + i) * 256 + c], hh, ll);
                ch[i] = hh; cl[i] = ll;
            }
            BhhH[kt][n] = ch; BhhL[kt][n] = cl;
        }
        bias[n] = bih[c] + bhh[c];
    }

    // ---- zero buf0, stage small tables ----
    for (int i = tid; i < 64 * XSTR / 2; i += 256) ((int*)sX[0])[i] = 0;
    if (tid < 64)       sIE[tid] = W_ie[tid];
    else if (tid < 96)  sIE[tid] = b_ie[tid - 64];
    if (tid < 128)      sWse[tid] = Wse[tid];
    else if (tid < 192) sWse[tid] = bse[tid - 128];
    __syncthreads();

    const float2* hist2 = (const float2*)hist;
    const int ag = tid >> 2;          // agent this thread embeds (0..63)
    const int eb = (tid & 3) << 3;    // its 8 emb dims

    auto emb_store = [&](float2 xy, int buf) {
        short8 ev;
#pragma unroll
        for (int q = 0; q < 8; ++q) {
            int e = eb + q;
            float v = fmaf(xy.x, sIE[e], fmaf(xy.y, sIE[32 + e], sIE[64 + e]));
            ev[q] = bf16rne_(fmaxf(v, 0.0f));
        }
        *(short8*)(sX[buf] + ag * XSTR + eb) = ev;
    };
    emb_store(hist2[n0 + ag], 0);
    __syncthreads();

    float cst[4][4];
#pragma unroll
    for (int m = 0; m < 4; ++m)
#pragma unroll
        for (int r = 0; r < 4; ++r) cst[m][r] = 0.0f;

    for (int t = 0; t < T; ++t) {
        // PREFETCH: issue next-step hist load before the MFMA phase so its
        // latency hides under compute (value identical; scheduling only).
        float2 xy_next;
        if (t + 1 < T) xy_next = hist2[(size_t)(t + 1) * N + n0 + ag];

        const short* bR = sX[t & 1];
        short* bW = sX[(t + 1) & 1];
#pragma unroll
        for (int m = 0; m < 4; ++m) {
            const short* row = bR + ((m << 4) + l15) * XSTR + l4 * 8;
            short8 aE  = *(const short8*)(row);
            short8 aH0 = *(const short8*)(row + 32);
            short8 aH1 = *(const short8*)(row + 64);
            short8 aL0 = *(const short8*)(row + 96);
            short8 aL1 = *(const short8*)(row + 128);
            f32x4 acc[4];
#pragma unroll
            for (int n = 0; n < 4; ++n)
                acc[n] = (f32x4){bias[n], bias[n], bias[n], bias[n]};
#pragma unroll
            for (int n = 0; n < 4; ++n) {
                acc[n] = __builtin_amdgcn_mfma_f32_16x16x32_bf16(aE,  Bih[n],     acc[n], 0, 0, 0);
                acc[n] = __builtin_amdgcn_mfma_f32_16x16x32_bf16(aH0, BhhH[0][n], acc[n], 0, 0, 0);
                acc[n] = __builtin_amdgcn_mfma_f32_16x16x32_bf16(aL0, BhhH[0][n], acc[n], 0, 0, 0);
                acc[n] = __builtin_amdgcn_mfma_f32_16x16x32_bf16(aH0, BhhL[0][n], acc[n], 0, 0, 0);
                acc[n] = __builtin_amdgcn_mfma_f32_16x16x32_bf16(aH1, BhhH[1][n], acc[n], 0, 0, 0);
                acc[n] = __builtin_amdgcn_mfma_f32_16x16x32_bf16(aL1, BhhH[1][n], acc[n], 0, 0, 0);
                acc[n] = __builtin_amdgcn_mfma_f32_16x16x32_bf16(aH1, BhhL[1][n], acc[n], 0, 0, 0);
            }
#pragma unroll
            for (int r = 0; r < 4; ++r) {
                float i_ = sigmoid_(acc[0][r]);
                float f_ = sigmoid_(acc[1][r]);
                float g_ = tanh_(acc[2][r]);
                float o_ = sigmoid_(acc[3][r]);
                cst[m][r] = fmaf(f_, cst[m][r], i_ * g_);
                float h = o_ * tanh_(cst[m][r]);
                short hh = bf16tr_(h);
                short hl = bf16rne_(h - b2f_(hh));
                int rw = (m << 4) + (l4 << 2) + r;
                bW[rw * XSTR + 32 + jcol] = hh;
                bW[rw * XSTR + 96 + jcol] = hl;
                if (t == T - 1 && l4 == 0 && r == 0 && (m & 1) == 0)
                    sTgt[(m >> 1) * 64 + jcol] = h;   // exact scene-first h
            }
        }
        if (t + 1 < T) emb_store(xy_next, (t + 1) & 1);
        __syncthreads();
    }

    // ---- social pooling: rel into dead buffer, Wmp in regs, MFMA ----
    short* rb = sX[(T + 1) & 1];      // buffer NOT holding final h
    const short* hb = sX[T & 1];      // final h (hi+lo)
    {
        const float2* pos2 = (const float2*)hist_pos;
        float2 pa = pos2[n0 + ag];
        float2 pb = pos2[n0 + (ag & 32)];   // scene-first agent (P=32)
        float px = pa.x - pb.x, py = pa.y - pb.y;
        int ebq = (tid & 3) << 4;
        short8 r0v, r1v;
#pragma unroll
        for (int q = 0; q < 8; ++q) {
            int e = ebq + q;
            float v = fmaf(px, sWse[e], fmaf(py, sWse[64 + e], sWse[128 + e]));
            r0v[q] = bf16rne_(fmaxf(v, 0.0f));
        }
#pragma unroll
        for (int q = 0; q < 8; ++q) {
            int e = ebq + 8 + q;
            float v = fmaf(px, sWse[e], fmaf(py, sWse[64 + e], sWse[128 + e]));
            r1v[q] = bf16rne_(fmaxf(v, 0.0f));
        }
        *(short8*)(rb + ag * XSTR + ebq)     = r0v;
        *(short8*)(rb + ag * XSTR + ebq + 8) = r1v;
    }
    // Wmp fragments: rows kt*32.. (k<64: h, k>=64: rel), col = jcol
    short8 BmH[4], BmL[4];
#pragma unroll
    for (int kt = 0; kt < 4; ++kt) {
        short8 bh, bl;
#pragma unroll
        for (int i = 0; i < 8; ++i) {
            short hh, ll; split_(Wmp[(kt * 32 + l4 * 8 + i) * 64 + jcol], hh, ll);
            bh[i] = hh; bl[i] = ll;
        }
        BmH[kt] = bh; BmL[kt] = bl;
    }
    float bmpv = bmp[jcol];
    __syncthreads();

    float smax0 = -3.4e38f, smax1 = -3.4e38f;
#pragma unroll
    for (int m = 0; m < 4; ++m) {
        const short* row  = hb + ((m << 4) + l15) * XSTR + l4 * 8;
        const short* rrow = rb + ((m << 4) + l15) * XSTR + l4 * 8;
        short8 h0 = *(const short8*)(row + 32);
        short8 h1 = *(const short8*)(row + 64);
        short8 q0 = *(const short8*)(row + 96);
        short8 q1 = *(const short8*)(row + 128);
        short8 r0 = *(const short8*)(rrow);
        short8 r1 = *(const short8*)(rrow + 32);
        f32x4 pc = (f32x4){bmpv, bmpv, bmpv, bmpv};
        pc = __builtin_amdgcn_mfma_f32_16x16x32_bf16(h0, BmH[0], pc, 0, 0, 0);
        pc = __builtin_amdgcn_mfma_f32_16x16x32_bf16(q0, BmH[0], pc, 0, 0, 0);
        pc = __builtin_amdgcn_mfma_f32_16x16x32_bf16(h0, BmL[0], pc, 0, 0, 0);
        pc = __builtin_amdgcn_mfma_f32_16x16x32_bf16(h1, BmH[1], pc, 0, 0, 0);
        pc = __builtin_amdgcn_mfma_f32_16x16x32_bf16(q1, BmH[1], pc, 0, 0, 0);
        pc = __builtin_amdgcn_mfma_f32_16x16x32_bf16(h1, BmL[1], pc, 0, 0, 0);
        pc = __builtin_amdgcn_mfma_f32_16x16x32_bf16(r0, BmH[2], pc, 0, 0, 0);
        pc = __builtin_amdgcn_mfma_f32_16x16x32_bf16(r0, BmL[2], pc, 0, 0, 0);
        pc = __builtin_amdgcn_mfma_f32_16x16x32_bf16(r1, BmH[3], pc, 0, 0, 0);
        pc = __builtin_amdgcn_mfma_f32_16x16x32_bf16(r1, BmL[3], pc, 0, 0, 0);
        float mx = fmaxf(fmaxf(pc[0], pc[1]), fmaxf(pc[2], pc[3]));
        mx = fmaxf(mx, 0.0f);   // relu(max) == max(relu)
        if (m < 2) smax0 = fmaxf(smax0, mx); else smax1 = fmaxf(smax1, mx);
    }
    smax0 = fmaxf(smax0, __shfl_xor(smax0, 16));
    smax0 = fmaxf(smax0, __shfl_xor(smax0, 32));
    smax1 = fmaxf(smax1, __shfl_xor(smax1, 16));
    smax1 = fmaxf(smax1, __shfl_xor(smax1, 32));
    if (l4 == 0) {
        int sg = blockIdx.x << 1;
        encO[sg * 128 + jcol]      = smax0;
        encO[sg * 128 + 64 + jcol] = sTgt[jcol];
    } else if (l4 == 1) {
        int sg = (blockIdx.x << 1) + 1;
        encO[sg * 128 + jcol]      = smax1;
        encO[sg * 128 + 64 + jcol] = sTgt[64 + jcol];
    }
}

// ---------------------------------------------------------------------------
// Decoder: WG = 512 threads = 8 waves = 8 scenes (proven round 11).
// ---------------------------------------------------------------------------
__global__ __launch_bounds__(512, 2) void dec_kernel(
    const float* __restrict__ enc,    // [S,128] (ws)
    const float* __restrict__ Wih_d,  // [128,256]
    const float* __restrict__ Whh_d,  // [64,256]
    const float* __restrict__ bih_d,  // [256]
    const float* __restrict__ bhh_d,  // [256]
    const float* __restrict__ Wop,    // [64,2]
    const float* __restrict__ bop,    // [2]
    float* __restrict__ out,          // [TOUT,S,2]
    int S, int TOUT)
{
    __shared__ __align__(16) float sWh[16384];   // [k64][j64][G4]
    __shared__ __align__(16) float sHd[512];     // [w8][j64]

    const int tid = threadIdx.x;
    const int j = tid & 63;
    const int w = tid >> 6;
    const int s = (blockIdx.x << 3) + w;

    for (int idx = tid; idx < 64 * 256; idx += 512) {
        int k = idx >> 8, col = idx & 255;
        sWh[((k << 6) | (col & 63)) * 4 + (col >> 6)] = Whh_d[idx];
    }
    sHd[tid] = 0.0f;

    float gx0 = bih_d[j]       + bhh_d[j];
    float gx1 = bih_d[64 + j]  + bhh_d[64 + j];
    float gx2 = bih_d[128 + j] + bhh_d[128 + j];
    float gx3 = bih_d[192 + j] + bhh_d[192 + j];
    for (int k = 0; k < 128; ++k) {
        float ev = enc[s * 128 + k];
        const float* col = Wih_d + k * 256;
        gx0 = fmaf(ev, col[j], gx0);
        gx1 = fmaf(ev, col[64 + j], gx1);
        gx2 = fmaf(ev, col[128 + j], gx2);
        gx3 = fmaf(ev, col[192 + j], gx3);
    }
    float wop0 = Wop[j * 2], wop1 = Wop[j * 2 + 1];
    float bop0 = bop[0], bop1 = bop[1];

    __syncthreads();

    const float4* Wh4 = reinterpret_cast<const float4*>(sWh);
    const float4* H4  = reinterpret_cast<const float4*>(sHd);

    float c = 0.0f;
    for (int t = 0; t < TOUT; ++t) {
        float g0 = gx0, g1 = gx1, g2 = gx2, g3 = gx3;
#pragma unroll 4
        for (int kq = 0; kq < 16; ++kq) {
            float4 hv = H4[(w << 4) + kq];
            float4 w0 = Wh4[((kq * 4 + 0) << 6) + j];
            float4 w1 = Wh4[((kq * 4 + 1) << 6) + j];
            float4 w2 = Wh4[((kq * 4 + 2) << 6) + j];
            float4 w3 = Wh4[((kq * 4 + 3) << 6) + j];
            g0 += hv.x * w0.x + hv.y * w1.x + hv.z * w2.x + hv.w * w3.x;
            g1 += hv.x * w0.y + hv.y * w1.y + hv.z * w2.y + hv.w * w3.y;
            g2 += hv.x * w0.z + hv.y * w1.z + hv.z * w2.z + hv.w * w3.z;
            g3 += hv.x * w0.w + hv.y * w1.w + hv.z * w2.w + hv.w * w3.w;
        }
        float i_ = sigmoid_(g0);
        float f_ = sigmoid_(g1);
        float gg = tanh_(g2);
        float o_ = sigmoid_(g3);
        c = fmaf(f_, c, i_ * gg);
        float h = o_ * tanh_(c);

        float r0 = h * wop0, r1 = h * wop1;
#pragma unroll
        for (int off = 32; off > 0; off >>= 1) {
            r0 += __shfl_xor(r0, off);
            r1 += __shfl_xor(r1, off);
        }
        if (j == 0) {
            float* op = out + ((size_t)t * S + s) * 2;
            op[0] = r0 + bop0;
            op[1] = r1 + bop1;
        }
        sHd[(w << 6) + j] = h;   // own row; intra-wave ordering suffices
    }
}

extern "C" void kernel_launch(void* const* d_in, const int* in_sizes, int n_in,
                              void* d_out, int out_size, void* d_ws, size_t ws_size,
                              hipStream_t stream) {
    (void)n_in; (void)ws_size;
    const float* hist     = (const float*)d_in[0];
    const float* hist_pos = (const float*)d_in[1];
    const float* W_ie     = (const float*)d_in[2];
    const float* b_ie     = (const float*)d_in[3];
    const float* Wih_e    = (const float*)d_in[4];
    const float* Whh_e    = (const float*)d_in[5];
    const float* bih_e    = (const float*)d_in[6];
    const float* bhh_e    = (const float*)d_in[7];
    const float* Wse      = (const float*)d_in[8];
    const float* bse      = (const float*)d_in[9];
    const float* Wmp      = (const float*)d_in[10];
    const float* bmp      = (const float*)d_in[11];
    const float* Wih_d    = (const float*)d_in[12];
    const float* Whh_d    = (const float*)d_in[13];
    const float* bih_d    = (const float*)d_in[14];
    const float* bhh_d    = (const float*)d_in[15];
    const float* Wop      = (const float*)d_in[16];
    const float* bop      = (const float*)d_in[17];

    const int N = in_sizes[1] / 2;
    const int T = in_sizes[0] / (N * 2);
    const int S = in_sizes[18] - 1;
    const int TOUT = out_size / (S * 2);

    float* enc = (float*)d_ws;   // [S,128] = 2 MB

    enc_pool_kernel<<<dim3(N / 64), dim3(256), 0, stream>>>(
        hist, hist_pos, W_ie, b_ie, Wih_e, Whh_e, bih_e, bhh_e,
        Wse, bse, Wmp, bmp, enc, N, T);

    dec_kernel<<<dim3(S / 8), dim3(512), 0, stream>>>(
        enc, Wih_d, Whh_d, bih_d, bhh_d, Wop, bop, (float*)d_out, S, TOUT);
}